// Round 1
// baseline (6815.478 us; speedup 1.0000x reference)
//
#include <hip/hip_runtime.h>

constexpr int DIMD  = 512;
constexpr int TOK   = 4096;   // B*S
constexpr int SEQL  = 512;
constexpr int NHEAD = 8;
constexpr int PHD   = 64;
constexpr int FFD   = 2048;
constexpr int NVOC  = 32000;

typedef float f32x4 __attribute__((ext_vector_type(4)));
typedef short bf16x8 __attribute__((ext_vector_type(8)));

__device__ __forceinline__ unsigned short f2bf(float f) {
  union { float f; unsigned u; } v; v.f = f;
  unsigned r = v.u + 0x7fffu + ((v.u >> 16) & 1u);  // RNE
  return (unsigned short)(r >> 16);
}

// ---------------- GEMM: C = A[M,K] @ B[K,N] (+bias)(+relu), fp32 io, bf16 MFMA ----
// tile 128x128x32, 256 threads = 4 waves (2x2), each wave 64x64 = 4x4 MFMA tiles
template<bool BIAS, bool RELU>
__global__ __launch_bounds__(256)
void gemm_kernel(const float* __restrict__ A, const float* __restrict__ B,
                 float* __restrict__ C, const float* __restrict__ bias,
                 int M, int N, int K) {
  __shared__ __align__(16) unsigned short As[128][40];  // [m][k] pad 32->40
  __shared__ __align__(16) unsigned short Bs[128][40];  // [n][k] (B transposed)
  const int m0 = blockIdx.y * 128, n0 = blockIdx.x * 128;
  const int tid = threadIdx.x;
  const int lane = tid & 63, wid = tid >> 6;
  const int wm = (wid >> 1) * 64, wn = (wid & 1) * 64;
  const int quad = lane >> 4, l16 = lane & 15;
  f32x4 acc[4][4] = {};
  const int ar = tid >> 3, ac = (tid & 7) * 4;   // A stage: 32 rows/sweep x 8 f4
  const int bk = tid >> 5, bn = (tid & 31) * 4;  // B stage: 8 k-rows/sweep x 32 f4
  for (int k0 = 0; k0 < K; k0 += 32) {
#pragma unroll
    for (int it = 0; it < 4; ++it) {
      int r = ar + it * 32;
      float4 v = *reinterpret_cast<const float4*>(A + (size_t)(m0 + r) * K + k0 + ac);
      ushort4 hh;
      hh.x = f2bf(v.x); hh.y = f2bf(v.y); hh.z = f2bf(v.z); hh.w = f2bf(v.w);
      *reinterpret_cast<ushort4*>(&As[r][ac]) = hh;
    }
#pragma unroll
    for (int it = 0; it < 4; ++it) {
      int kk = bk + it * 8;
      float4 v = *reinterpret_cast<const float4*>(B + (size_t)(k0 + kk) * N + n0 + bn);
      Bs[bn + 0][kk] = f2bf(v.x);
      Bs[bn + 1][kk] = f2bf(v.y);
      Bs[bn + 2][kk] = f2bf(v.z);
      Bs[bn + 3][kk] = f2bf(v.w);
    }
    __syncthreads();
    bf16x8 af[4], bb[4];
#pragma unroll
    for (int i = 0; i < 4; ++i)
      af[i] = *reinterpret_cast<const bf16x8*>(&As[wm + i * 16 + l16][quad * 8]);
#pragma unroll
    for (int j = 0; j < 4; ++j)
      bb[j] = *reinterpret_cast<const bf16x8*>(&Bs[wn + j * 16 + l16][quad * 8]);
#pragma unroll
    for (int i = 0; i < 4; ++i)
#pragma unroll
      for (int j = 0; j < 4; ++j)
        acc[i][j] = __builtin_amdgcn_mfma_f32_16x16x32_bf16(af[i], bb[j], acc[i][j], 0, 0, 0);
    __syncthreads();
  }
#pragma unroll
  for (int i = 0; i < 4; ++i) {
    const int row = m0 + wm + i * 16 + quad * 4;
#pragma unroll
    for (int j = 0; j < 4; ++j) {
      const int col = n0 + wn + j * 16 + l16;
      float bv = 0.f;
      if (BIAS) bv = bias[col];
#pragma unroll
      for (int r = 0; r < 4; ++r) {
        float v = acc[i][j][r] + bv;
        if (RELU) v = fmaxf(v, 0.f);
        C[(size_t)(row + r) * N + col] = v;
      }
    }
  }
}

// ---------------- Fused flash attention ----------------
// grid (S/64, H, B), 256 thr = 4 waves, each wave 16 q rows. K/V staged 32 keys/iter.
template<bool CAUSAL>
__global__ __launch_bounds__(256)
void attn_kernel(const float* __restrict__ Q, const float* __restrict__ K,
                 const float* __restrict__ V, float* __restrict__ O,
                 const int* __restrict__ kv_ids) {
  __shared__ __align__(16) unsigned short Ks[32][72];     // [s][d] natural (B-op for QK^T)
  __shared__ __align__(16) unsigned short Vs[64][40];     // [d][s] transposed (B-op for PV)
  __shared__ __align__(16) unsigned short Ps[4][16][40];  // per-wave P tile [q][k]
  const int b = blockIdx.z, h = blockIdx.y, q0 = blockIdx.x * 64;
  const int tid = threadIdx.x, wv = tid >> 6, lane = tid & 63;
  const int quad = lane >> 4, l16 = lane & 15;
  const int qrow = q0 + wv * 16 + l16;
  // Q fragments (A-operand): lane holds Q[m=l16][k = half*32 + quad*8 + j]
  const float* qp = Q + (size_t)(b * SEQL + qrow) * DIMD + h * PHD;
  bf16x8 qf[2];
#pragma unroll
  for (int hf = 0; hf < 2; ++hf) {
    const float* p = qp + hf * 32 + quad * 8;
    float4 v0 = *reinterpret_cast<const float4*>(p);
    float4 v1 = *reinterpret_cast<const float4*>(p + 4);
    bf16x8 q8;
    q8[0] = (short)f2bf(v0.x); q8[1] = (short)f2bf(v0.y);
    q8[2] = (short)f2bf(v0.z); q8[3] = (short)f2bf(v0.w);
    q8[4] = (short)f2bf(v1.x); q8[5] = (short)f2bf(v1.y);
    q8[6] = (short)f2bf(v1.z); q8[7] = (short)f2bf(v1.w);
    qf[hf] = q8;
  }
  float m_r[4] = {-1e30f, -1e30f, -1e30f, -1e30f};
  float l_r[4] = {0.f, 0.f, 0.f, 0.f};
  f32x4 Oacc[4] = {};
  const int ss = tid >> 3, d8 = (tid & 7) * 8;  // staging: 32 rows x 8 lanes x 8 floats
  for (int k0 = 0; k0 < SEQL; k0 += 32) {
    {
      const float* kp = K + (size_t)(b * SEQL + k0 + ss) * DIMD + h * PHD + d8;
      float4 a = *reinterpret_cast<const float4*>(kp);
      float4 c = *reinterpret_cast<const float4*>(kp + 4);
      ushort4 h0, h1;
      h0.x = f2bf(a.x); h0.y = f2bf(a.y); h0.z = f2bf(a.z); h0.w = f2bf(a.w);
      h1.x = f2bf(c.x); h1.y = f2bf(c.y); h1.z = f2bf(c.z); h1.w = f2bf(c.w);
      *reinterpret_cast<ushort4*>(&Ks[ss][d8]) = h0;
      *reinterpret_cast<ushort4*>(&Ks[ss][d8 + 4]) = h1;
      const float* vp = V + (size_t)(b * SEQL + k0 + ss) * DIMD + h * PHD + d8;
      float4 e = *reinterpret_cast<const float4*>(vp);
      float4 f = *reinterpret_cast<const float4*>(vp + 4);
      Vs[d8 + 0][ss] = f2bf(e.x); Vs[d8 + 1][ss] = f2bf(e.y);
      Vs[d8 + 2][ss] = f2bf(e.z); Vs[d8 + 3][ss] = f2bf(e.w);
      Vs[d8 + 4][ss] = f2bf(f.x); Vs[d8 + 5][ss] = f2bf(f.y);
      Vs[d8 + 6][ss] = f2bf(f.z); Vs[d8 + 7][ss] = f2bf(f.w);
    }
    __syncthreads();
    // scores: two 16x16 tiles over this 32-key chunk, K-dim = ph (2 MFMAs each)
    f32x4 sc[2];
#pragma unroll
    for (int c = 0; c < 2; ++c) {
      bf16x8 kf0 = *reinterpret_cast<const bf16x8*>(&Ks[c * 16 + l16][quad * 8]);
      bf16x8 kf1 = *reinterpret_cast<const bf16x8*>(&Ks[c * 16 + l16][32 + quad * 8]);
      f32x4 t = {};
      t = __builtin_amdgcn_mfma_f32_16x16x32_bf16(qf[0], kf0, t, 0, 0, 0);
      t = __builtin_amdgcn_mfma_f32_16x16x32_bf16(qf[1], kf1, t, 0, 0, 0);
      sc[c] = t;
    }
    float alpha[4];
#pragma unroll
    for (int r = 0; r < 4; ++r) {
      const int qg = q0 + wv * 16 + quad * 4 + r;
      float sv0, sv1;
      {
        int col = k0 + l16;
        bool ok = (kv_ids[b * SEQL + col] != 0);
        if (CAUSAL) ok = ok && (col <= qg);
        sv0 = ok ? sc[0][r] * 0.125f : -1e9f;
        col = k0 + 16 + l16;
        ok = (kv_ids[b * SEQL + col] != 0);
        if (CAUSAL) ok = ok && (col <= qg);
        sv1 = ok ? sc[1][r] * 0.125f : -1e9f;
      }
      float mx = fmaxf(sv0, sv1);
#pragma unroll
      for (int off = 1; off < 16; off <<= 1) mx = fmaxf(mx, __shfl_xor(mx, off));
      float mnew = fmaxf(m_r[r], mx);
      alpha[r] = __expf(m_r[r] - mnew);
      float p0 = __expf(sv0 - mnew);
      float p1 = __expf(sv1 - mnew);
      float ps = p0 + p1;
#pragma unroll
      for (int off = 1; off < 16; off <<= 1) ps += __shfl_xor(ps, off);
      l_r[r] = l_r[r] * alpha[r] + ps;
      m_r[r] = mnew;
      // store P in D-layout -> read back in A-layout (wave-private, in-order LDS)
      Ps[wv][quad * 4 + r][l16] = f2bf(p0);
      Ps[wv][quad * 4 + r][16 + l16] = f2bf(p1);
    }
#pragma unroll
    for (int j = 0; j < 4; ++j)
#pragma unroll
      for (int r = 0; r < 4; ++r) Oacc[j][r] *= alpha[r];
    __builtin_amdgcn_wave_barrier();
    bf16x8 pf = *reinterpret_cast<const bf16x8*>(&Ps[wv][l16][quad * 8]);
#pragma unroll
    for (int j = 0; j < 4; ++j) {
      bf16x8 vf = *reinterpret_cast<const bf16x8*>(&Vs[j * 16 + l16][quad * 8]);
      Oacc[j] = __builtin_amdgcn_mfma_f32_16x16x32_bf16(pf, vf, Oacc[j], 0, 0, 0);
    }
    __syncthreads();
  }
#pragma unroll
  for (int r = 0; r < 4; ++r) {
    const int row = q0 + wv * 16 + quad * 4 + r;
    const float inv = 1.f / l_r[r];
    float* op = O + (size_t)(b * SEQL + row) * DIMD + h * PHD;
#pragma unroll
    for (int j = 0; j < 4; ++j) op[j * 16 + l16] = Oacc[j][r] * inv;
  }
}

// ---------------- out = LayerNorm(x + y) * g + b  (one wave per row, in-place ok) --
__global__ __launch_bounds__(256)
void ln_add_kernel(const float* x, const float* __restrict__ y,
                   const float* __restrict__ g, const float* __restrict__ bb,
                   float* out) {
  const int row = blockIdx.x * 4 + (threadIdx.x >> 6);
  const int lane = threadIdx.x & 63;
  const float* xp = x + (size_t)row * DIMD + lane * 8;
  const float* yp = y + (size_t)row * DIMD + lane * 8;
  float4 a0 = *reinterpret_cast<const float4*>(xp);
  float4 a1 = *reinterpret_cast<const float4*>(xp + 4);
  float4 b0 = *reinterpret_cast<const float4*>(yp);
  float4 b1 = *reinterpret_cast<const float4*>(yp + 4);
  float v[8] = {a0.x + b0.x, a0.y + b0.y, a0.z + b0.z, a0.w + b0.w,
                a1.x + b1.x, a1.y + b1.y, a1.z + b1.z, a1.w + b1.w};
  float s = 0.f;
#pragma unroll
  for (int i = 0; i < 8; ++i) s += v[i];
#pragma unroll
  for (int off = 32; off > 0; off >>= 1) s += __shfl_xor(s, off);
  const float mean = s * (1.0f / DIMD);
  float q = 0.f;
#pragma unroll
  for (int i = 0; i < 8; ++i) { float d = v[i] - mean; q += d * d; }
#pragma unroll
  for (int off = 32; off > 0; off >>= 1) q += __shfl_xor(q, off);
  const float rs = rsqrtf(q * (1.0f / DIMD) + 1e-5f);
  const float* gp = g + lane * 8;
  const float* bp = bb + lane * 8;
  float o[8];
#pragma unroll
  for (int i = 0; i < 8; ++i) o[i] = (v[i] - mean) * rs * gp[i] + bp[i];
  float* op = out + (size_t)row * DIMD + lane * 8;
  float4 w0 = {o[0], o[1], o[2], o[3]};
  float4 w1 = {o[4], o[5], o[6], o[7]};
  *reinterpret_cast<float4*>(op) = w0;
  *reinterpret_cast<float4*>(op + 4) = w1;
}

// ---------------- x = emb[id]*sqrt(D) + pe ----------------
__global__ __launch_bounds__(256)
void embed_kernel(const int* __restrict__ ids, const float* __restrict__ emb,
                  float* __restrict__ out) {
  const int t = blockIdx.x;
  const int s = t & (SEQL - 1);
  const int id = ids[t];
  const int d = threadIdx.x * 2;
  float2 e = *reinterpret_cast<const float2*>(emb + (size_t)id * DIMD + d);
  const float c = -0.017988946039015984f;  // -ln(10000)/512
  const float div = expf((float)d * c);
  const float ang = (float)s * div;
  const float sq = 22.627416997969522f;    // sqrt(512)
  float2 o;
  o.x = e.x * sq + sinf(ang);
  o.y = e.y * sq + cosf(ang);
  *reinterpret_cast<float2*>(out + (size_t)t * DIMD + d) = o;
}

extern "C" void kernel_launch(void* const* d_in, const int* in_sizes, int n_in,
                              void* d_out, int out_size, void* d_ws, size_t ws_size,
                              hipStream_t stream) {
  (void)in_sizes; (void)n_in; (void)out_size; (void)ws_size;
  const int*   input   = (const int*)d_in[0];
  const int*   target  = (const int*)d_in[1];
  const float* emb     = (const float*)d_in[2];
  const float* out_w   = (const float*)d_in[3];
  const float* out_b   = (const float*)d_in[4];
  const float* e_wq    = (const float*)d_in[5];
  const float* e_wk    = (const float*)d_in[6];
  const float* e_wv    = (const float*)d_in[7];
  const float* e_wo    = (const float*)d_in[8];
  const float* e_ff1_w = (const float*)d_in[9];
  const float* e_ff1_b = (const float*)d_in[10];
  const float* e_ff2_w = (const float*)d_in[11];
  const float* e_ff2_b = (const float*)d_in[12];
  const float* e_ln1_g = (const float*)d_in[13];
  const float* e_ln1_b = (const float*)d_in[14];
  const float* e_ln2_g = (const float*)d_in[15];
  const float* e_ln2_b = (const float*)d_in[16];
  const float* d_swq   = (const float*)d_in[17];
  const float* d_swk   = (const float*)d_in[18];
  const float* d_swv   = (const float*)d_in[19];
  const float* d_swo   = (const float*)d_in[20];
  const float* d_cwq   = (const float*)d_in[21];
  const float* d_cwk   = (const float*)d_in[22];
  const float* d_cwv   = (const float*)d_in[23];
  const float* d_cwo   = (const float*)d_in[24];
  const float* d_ff1_w = (const float*)d_in[25];
  const float* d_ff1_b = (const float*)d_in[26];
  const float* d_ff2_w = (const float*)d_in[27];
  const float* d_ff2_b = (const float*)d_in[28];
  const float* d_ln1_g = (const float*)d_in[29];
  const float* d_ln1_b = (const float*)d_in[30];
  const float* d_ln2_g = (const float*)d_in[31];
  const float* d_ln2_b = (const float*)d_in[32];
  const float* d_ln3_g = (const float*)d_in[33];
  const float* d_ln3_b = (const float*)d_in[34];

  const size_t TD = (size_t)TOK * DIMD;   // 2M floats
  const size_t DD = (size_t)DIMD * DIMD;
  const size_t DF = (size_t)DIMD * FFD;
  float* ws   = (float*)d_ws;
  float* xe   = ws;            // encoder activations -> enc_out (8 MB)
  float* xd   = ws + TD;       // decoder activations (8 MB)
  float* yb   = ws + 2 * TD;   // sublayer output (8 MB)
  float* pool = ws + 3 * TD;   // TOK*FFD floats (32 MB); aliases q/k/v/ctx
  float* qb = pool;
  float* kb = pool + TD;
  float* vb = pool + 2 * TD;
  float* cb = pool + 3 * TD;

  dim3 blk(256);
  dim3 ag(SEQL / 64, NHEAD, 8);

  auto gemm = [&](const float* A, const float* B, float* C, const float* bias,
                  int M, int N, int K, bool relu) {
    dim3 g(N / 128, M / 128);
    if (bias) {
      if (relu) gemm_kernel<true, true><<<g, blk, 0, stream>>>(A, B, C, bias, M, N, K);
      else      gemm_kernel<true, false><<<g, blk, 0, stream>>>(A, B, C, bias, M, N, K);
    } else {
      gemm_kernel<false, false><<<g, blk, 0, stream>>>(A, B, C, nullptr, M, N, K);
    }
  };

  embed_kernel<<<TOK, blk, 0, stream>>>(input, emb, xe);
  embed_kernel<<<TOK, blk, 0, stream>>>(target, emb, xd);

  for (int l = 0; l < 6; ++l) {
    gemm(xe, e_wq + l * DD, qb, nullptr, TOK, DIMD, DIMD, false);
    gemm(xe, e_wk + l * DD, kb, nullptr, TOK, DIMD, DIMD, false);
    gemm(xe, e_wv + l * DD, vb, nullptr, TOK, DIMD, DIMD, false);
    attn_kernel<false><<<ag, blk, 0, stream>>>(qb, kb, vb, cb, input);
    gemm(cb, e_wo + l * DD, yb, nullptr, TOK, DIMD, DIMD, false);
    ln_add_kernel<<<TOK / 4, blk, 0, stream>>>(xe, yb, e_ln1_g + l * DIMD, e_ln1_b + l * DIMD, xe);
    gemm(xe, e_ff1_w + l * DF, pool, e_ff1_b + l * FFD, TOK, FFD, DIMD, true);
    gemm(pool, e_ff2_w + l * DF, yb, e_ff2_b + l * DIMD, TOK, DIMD, FFD, false);
    ln_add_kernel<<<TOK / 4, blk, 0, stream>>>(xe, yb, e_ln2_g + l * DIMD, e_ln2_b + l * DIMD, xe);
  }

  for (int l = 0; l < 6; ++l) {
    // masked self-attention
    gemm(xd, d_swq + l * DD, qb, nullptr, TOK, DIMD, DIMD, false);
    gemm(xd, d_swk + l * DD, kb, nullptr, TOK, DIMD, DIMD, false);
    gemm(xd, d_swv + l * DD, vb, nullptr, TOK, DIMD, DIMD, false);
    attn_kernel<true><<<ag, blk, 0, stream>>>(qb, kb, vb, cb, target);
    gemm(cb, d_swo + l * DD, yb, nullptr, TOK, DIMD, DIMD, false);
    ln_add_kernel<<<TOK / 4, blk, 0, stream>>>(xd, yb, d_ln1_g + l * DIMD, d_ln1_b + l * DIMD, xd);
    // cross-attention (KV from encoder output)
    gemm(xd, d_cwq + l * DD, qb, nullptr, TOK, DIMD, DIMD, false);
    gemm(xe, d_cwk + l * DD, kb, nullptr, TOK, DIMD, DIMD, false);
    gemm(xe, d_cwv + l * DD, vb, nullptr, TOK, DIMD, DIMD, false);
    attn_kernel<false><<<ag, blk, 0, stream>>>(qb, kb, vb, cb, input);
    gemm(cb, d_cwo + l * DD, yb, nullptr, TOK, DIMD, DIMD, false);
    ln_add_kernel<<<TOK / 4, blk, 0, stream>>>(xd, yb, d_ln2_g + l * DIMD, d_ln2_b + l * DIMD, xd);
    // FF
    gemm(xd, d_ff1_w + l * DF, pool, d_ff1_b + l * FFD, TOK, FFD, DIMD, true);
    gemm(pool, d_ff2_w + l * DF, yb, d_ff2_b + l * DIMD, TOK, DIMD, FFD, false);
    ln_add_kernel<<<TOK / 4, blk, 0, stream>>>(xd, yb, d_ln3_g + l * DIMD, d_ln3_b + l * DIMD, xd);
  }

  // final vocab projection straight into d_out
  gemm(xd, out_w, (float*)d_out, out_b, TOK, NVOC, DIMD, false);
}